// Round 12
// baseline (1293.690 us; speedup 1.0000x reference)
//
#include <hip/hip_runtime.h>
#include <math.h>

#define N_NODES 8000
#define N_EDGES 64000
#define ETOT    (N_EDGES + N_NODES)   // 72000, self-loops appended
#define EDIM    16
#define NGRAPHS 64

typedef __attribute__((ext_vector_type(8))) short short8v;
typedef __attribute__((ext_vector_type(4))) short short4v;
typedef __attribute__((ext_vector_type(4))) float f32x4;

__device__ inline unsigned short f2bf(float f) {
    unsigned u = __builtin_bit_cast(unsigned, f);
    unsigned r = (u + 0x7FFF + ((u >> 16) & 1)) >> 16;   // RNE
    return (unsigned short)r;
}
__device__ inline float bf2f(unsigned short b) {
    unsigned u = ((unsigned)b) << 16;
    return __builtin_bit_cast(float, u);
}

// ---------------- CSR build ----------------

__global__ void count_deg(const int* __restrict__ dst0, int* __restrict__ deg) {
    int e = blockIdx.x * 256 + threadIdx.x;
    if (e < N_EDGES) atomicAdd(&deg[dst0[e]], 1);
}

__global__ void scan_deg(const int* __restrict__ deg, int* __restrict__ rowptr) {
    __shared__ int sh[256];
    __shared__ int carry_s;
    int t = threadIdx.x;
    if (t == 0) { carry_s = 0; rowptr[0] = 0; }
    __syncthreads();
    for (int base = 0; base < N_NODES; base += 256) {
        int i = base + t;
        int v = (i < N_NODES) ? (deg[i] + 1) : 0;   // +1 self loop
        sh[t] = v;
        __syncthreads();
        for (int off = 1; off < 256; off <<= 1) {
            int u = (t >= off) ? sh[t - off] : 0;
            __syncthreads();
            sh[t] += u;
            __syncthreads();
        }
        int incl = sh[t] + carry_s;
        if (i < N_NODES) rowptr[i + 1] = incl;
        __syncthreads();
        if (t == 255) carry_s = incl;
        __syncthreads();
    }
}

__global__ void copy_off(const int* __restrict__ rowptr, int* __restrict__ woff) {
    int i = blockIdx.x * 256 + threadIdx.x;
    if (i < N_NODES) woff[i] = rowptr[i];
}

__global__ void fill_eid(const int* __restrict__ dst0, int* __restrict__ woff,
                         int* __restrict__ eid) {
    int i = blockIdx.x * 256 + threadIdx.x;
    if (i < N_EDGES) {
        int pos = atomicAdd(&woff[dst0[i]], 1);
        eid[pos] = i;
    } else if (i < ETOT) {
        int n = i - N_EDGES;
        int pos = atomicAdd(&woff[n], 1);
        eid[pos] = i;
    }
}

__global__ void csr_fill_dst(const int* __restrict__ rowptr, int* __restrict__ csr_dst) {
    int n = blockIdx.x * 256 + threadIdx.x;
    if (n >= N_NODES) return;
    int b = rowptr[n], t = rowptr[n + 1];
    for (int i = b; i < t; i++) csr_dst[i] = n;
}

__global__ void ea_loop_kernel(const int* __restrict__ rowptr, const int* __restrict__ eid,
                               const float* __restrict__ edge_attr, float* __restrict__ ea_loop) {
    int n = blockIdx.x * 256 + threadIdx.x;
    if (n >= N_NODES) return;
    float s[EDIM];
#pragma unroll
    for (int k = 0; k < EDIM; k++) s[k] = 0.f;
    int cnt = 0;
    int b = rowptr[n], t = rowptr[n + 1];
    for (int i = b; i < t; i++) {
        int e = eid[i];
        if (e < N_EDGES) {
            cnt++;
            const float* ea = edge_attr + (size_t)e * EDIM;
#pragma unroll
            for (int k = 0; k < EDIM; k++) s[k] += ea[k];
        }
    }
    float inv = 1.f / (float)(cnt > 0 ? cnt : 1);
#pragma unroll
    for (int k = 0; k < EDIM; k++) ea_loop[(size_t)n * EDIM + k] = s[k] * inv;
}

__global__ void csr_srcea(const int* __restrict__ eid, const int* __restrict__ src0,
                          const float* __restrict__ edge_attr, const float* __restrict__ ea_loop,
                          int* __restrict__ csr_src, float* __restrict__ ea_csr) {
    int t = blockIdx.x * 256 + threadIdx.x;
    int i = t >> 2, q = t & 3;
    if (i >= ETOT) return;
    int e = eid[i];
    int s = (e < N_EDGES) ? src0[e] : (e - N_EDGES);
    if (q == 0) csr_src[i] = s;
    const float* ea = (e < N_EDGES) ? edge_attr + (size_t)e * EDIM
                                    : ea_loop + (size_t)(e - N_EDGES) * EDIM;
    *(float4*)(ea_csr + (size_t)i * EDIM + q * 4) = *(const float4*)(ea + q * 4);
}

// ea bf16 hi/lo split in MFMA B-layout rows [edge][32] (k padded 16->32 w/ zeros)
__global__ void cvt_ea(const float* __restrict__ ea_csr,
                       short* __restrict__ eah, short* __restrict__ eal) {
    int t = blockIdx.x * 256 + threadIdx.x;
    if (t >= ETOT * EDIM) return;
    int e = t >> 4, k = t & 15;
    float v = ea_csr[(size_t)e * EDIM + k];
    unsigned short h = f2bf(v);
    unsigned short l = f2bf(v - bf2f(h));
    eah[(size_t)e * 32 + k] = (short)h;
    eal[(size_t)e * 32 + k] = (short)l;
    eah[(size_t)e * 32 + 16 + k] = 0;
    eal[(size_t)e * 32 + 16 + k] = 0;
}

// We [16][hc] -> WeT hi/lo [hc][32] (A-operand layout, k padded w/ zeros)
__global__ void cvt_we(const float* __restrict__ We,
                       short* __restrict__ weTh, short* __restrict__ weTl, int hc) {
    int ch = blockIdx.x * 256 + threadIdx.x;
    if (ch >= hc) return;
#pragma unroll
    for (int k = 0; k < EDIM; k++) {
        float v = We[(size_t)k * hc + ch];
        unsigned short h = f2bf(v);
        unsigned short l = f2bf(v - bf2f(h));
        weTh[(size_t)ch * 32 + k] = (short)h;
        weTl[(size_t)ch * 32 + k] = (short)l;
    }
#pragma unroll
    for (int k = EDIM; k < 32; k++) {
        weTh[(size_t)ch * 32 + k] = 0;
        weTl[(size_t)ch * 32 + k] = 0;
    }
}

// ---------------- weight transpose + bf16 split: W[K][N] -> WT_hi/lo[N][K] ----------------

__global__ __launch_bounds__(256) void cvt_wt_t(
        const float* __restrict__ W, short* __restrict__ WTh, short* __restrict__ WTl,
        int K, int Nc) {
    __shared__ float sh[32][33];
    int t = threadIdx.x;
    int tx = t & 31, ty = t >> 5;            // 32 x 8
    int n0 = blockIdx.x * 32, k0 = blockIdx.y * 32;
#pragma unroll
    for (int j = 0; j < 4; j++)
        sh[ty + j * 8][tx] = W[(size_t)(k0 + ty + j * 8) * Nc + n0 + tx];
    __syncthreads();
#pragma unroll
    for (int j = 0; j < 4; j++) {
        int row = ty + j * 8;                 // local n
        float v = sh[tx][row];
        unsigned short h = f2bf(v);
        unsigned short l = f2bf(v - bf2f(h));
        size_t idx = (size_t)(n0 + row) * K + k0 + tx;
        WTh[idx] = (short)h;
        WTl[idx] = (short)l;
    }
}

// ---------------- activation bf16 hi/lo pre-split (layer-1 input only) ----------------

__global__ __launch_bounds__(256) void cvt_act(
        const float* __restrict__ in, short* __restrict__ acth, short* __restrict__ actl,
        int total /* M*K, multiple of 4 */) {
    int i = blockIdx.x * 256 + threadIdx.x;
    if (i * 4 >= total) return;
    float4 v = *(const float4*)(in + (size_t)i * 4);
    unsigned short h0 = f2bf(v.x), h1 = f2bf(v.y), h2 = f2bf(v.z), h3 = f2bf(v.w);
    short4v hv = { (short)h0, (short)h1, (short)h2, (short)h3 };
    short4v lv = { (short)f2bf(v.x - bf2f(h0)), (short)f2bf(v.y - bf2f(h1)),
                   (short)f2bf(v.z - bf2f(h2)), (short)f2bf(v.w - bf2f(h3)) };
    *(short4v*)(acth + (size_t)i * 4) = hv;
    *(short4v*)(actl + (size_t)i * 4) = lv;
}

// ---------------- bf16x3 MFMA GEMM, A pre-split, fused Wl|Wr (dual bias) ----------------
// Staging mapping srow = t&127, sseg = t>>7: each 8-lane group writes 8
// consecutive rows (same seg) -> LDS bank starts (20r+8s)%32 all distinct
// (the old (t>>1,t&1) mapping collided: 2.5e7 conflict cycles at L2).

#define LDK 40   // padded LDS row stride in shorts (32 + 8)

__global__ __launch_bounds__(256) void gemm_mfma2(
        const short* __restrict__ Ah_g, const short* __restrict__ Al_g,
        const short* __restrict__ BTh, const short* __restrict__ BTl,
        const float* __restrict__ bias1, const float* __restrict__ bias2, int hsplit,
        float* __restrict__ C, int M, int K, int Nc) {
    __shared__ short Ah[128 * LDK];
    __shared__ short Al[128 * LDK];
    __shared__ short Bh[128 * LDK];
    __shared__ short Bl[128 * LDK];
    int t = threadIdx.x;
    int m0 = blockIdx.y * 128, n0 = blockIdx.x * 128;
    int lane = t & 63, wave = t >> 6;
    int wm = (wave >> 1) * 64, wn = (wave & 1) * 64;
    int fr = lane & 15, koff = (lane >> 4) * 8;

    f32x4 acc[4][4];
#pragma unroll
    for (int i = 0; i < 4; i++)
#pragma unroll
        for (int j = 0; j < 4; j++) acc[i][j] = (f32x4)(0.f);

    int srow = t & 127, sseg = t >> 7;        // conflict-free staging mapping

    for (int k0 = 0; k0 < K; k0 += 32) {
        __syncthreads();
        {
            const short* ga_h = Ah_g + (size_t)(m0 + srow) * K + k0 + sseg * 16;
            const short* ga_l = Al_g + (size_t)(m0 + srow) * K + k0 + sseg * 16;
            const short* gb_h = BTh + (size_t)(n0 + srow) * K + k0 + sseg * 16;
            const short* gb_l = BTl + (size_t)(n0 + srow) * K + k0 + sseg * 16;
            int lo = srow * LDK + sseg * 16;
            *(short8v*)&Ah[lo]     = *(const short8v*)ga_h;
            *(short8v*)&Ah[lo + 8] = *(const short8v*)(ga_h + 8);
            *(short8v*)&Al[lo]     = *(const short8v*)ga_l;
            *(short8v*)&Al[lo + 8] = *(const short8v*)(ga_l + 8);
            *(short8v*)&Bh[lo]     = *(const short8v*)gb_h;
            *(short8v*)&Bh[lo + 8] = *(const short8v*)(gb_h + 8);
            *(short8v*)&Bl[lo]     = *(const short8v*)gb_l;
            *(short8v*)&Bl[lo + 8] = *(const short8v*)(gb_l + 8);
        }
        __syncthreads();

        short8v ah[4], al[4], bh[4], bl[4];
#pragma unroll
        for (int mi = 0; mi < 4; mi++) {
            int r = (wm + mi * 16 + fr) * LDK + koff;
            ah[mi] = *(short8v*)&Ah[r];
            al[mi] = *(short8v*)&Al[r];
        }
#pragma unroll
        for (int ni = 0; ni < 4; ni++) {
            int r = (wn + ni * 16 + fr) * LDK + koff;
            bh[ni] = *(short8v*)&Bh[r];
            bl[ni] = *(short8v*)&Bl[r];
        }
#pragma unroll
        for (int mi = 0; mi < 4; mi++)
#pragma unroll
            for (int ni = 0; ni < 4; ni++) {
                acc[mi][ni] = __builtin_amdgcn_mfma_f32_16x16x32_bf16(
                    al[mi], bh[ni], acc[mi][ni], 0, 0, 0);
                acc[mi][ni] = __builtin_amdgcn_mfma_f32_16x16x32_bf16(
                    ah[mi], bl[ni], acc[mi][ni], 0, 0, 0);
                acc[mi][ni] = __builtin_amdgcn_mfma_f32_16x16x32_bf16(
                    ah[mi], bh[ni], acc[mi][ni], 0, 0, 0);
            }
    }

    int rbase = (lane >> 4) * 4;
#pragma unroll
    for (int ni = 0; ni < 4; ni++) {
        int col = n0 + wn + ni * 16 + fr;
        const float* bp = (col < hsplit) ? bias1 + col : bias2 + (col - hsplit);
        float bz = *bp;
#pragma unroll
        for (int mi = 0; mi < 4; mi++) {
            int row0 = m0 + wm + mi * 16 + rbase;
#pragma unroll
            for (int r = 0; r < 4; r++) {
                int row = row0 + r;
                if (row < M) C[(size_t)row * Nc + col] = acc[mi][ni][r] + bz;
            }
        }
    }
}

// ---------------- edge logits v7: MFMA ee, per-head block, 2-deep pipeline ----------------

__global__ __launch_bounds__(256, 4) void edge_logits7(
        const float* __restrict__ xl, const float* __restrict__ xr,
        const short* __restrict__ weTh, const short* __restrict__ weTl,
        const float* __restrict__ att,
        const short* __restrict__ eah, const short* __restrict__ eal,
        const int* __restrict__ csr_src, const int* __restrict__ csr_dst,
        float* __restrict__ logits, int H, int co, int stride) {
    int tid = threadIdx.x;
    int lane = tid & 63, wave = tid >> 6;
    int head = blockIdx.y;
    int cbase = head * co;
    int e0 = blockIdx.x * 64 + wave * 16;    // ETOT % 64 == 0
    int col = lane & 15;                     // edge within tile
    int quad = lane >> 4;
    int e = e0 + col;
    int s = csr_src[e], d = csr_dst[e];
    int ch0 = cbase + quad * 4;

    short8v bh = *(const short8v*)(eah + (size_t)e * 32 + quad * 8);
    short8v bl = *(const short8v*)(eal + (size_t)e * 32 + quad * 8);

    const float* xls = xl + (size_t)s * stride + ch0;
    const float* xrd = xr + (size_t)d * stride + ch0;
    const float* atp = att + ch0;
    const short* wph = weTh + (size_t)(cbase + col) * 32 + quad * 8;
    const short* wpl = weTl + (size_t)(cbase + col) * 32 + quad * 8;

    int ntile = co >> 4;
    float p = 0.f;

    short8v ahA = *(const short8v*)wph;
    short8v alA = *(const short8v*)wpl;
    float4 lvA = *(const float4*)xls;
    float4 rvA = *(const float4*)xrd;
    float4 avA = *(const float4*)atp;

    for (int tt = 0; tt < ntile - 1; tt++) {
        short8v ahB = *(const short8v*)(wph + (size_t)(tt + 1) * 512);
        short8v alB = *(const short8v*)(wpl + (size_t)(tt + 1) * 512);
        float4 lvB = *(const float4*)(xls + (tt + 1) * 16);
        float4 rvB = *(const float4*)(xrd + (tt + 1) * 16);
        float4 avB = *(const float4*)(atp + (tt + 1) * 16);

        f32x4 ee = (f32x4)(0.f);
        ee = __builtin_amdgcn_mfma_f32_16x16x32_bf16(ahA, bl, ee, 0, 0, 0);
        ee = __builtin_amdgcn_mfma_f32_16x16x32_bf16(alA, bh, ee, 0, 0, 0);
        ee = __builtin_amdgcn_mfma_f32_16x16x32_bf16(ahA, bh, ee, 0, 0, 0);
        float m0 = lvA.x + rvA.x + ee[0];
        float m1 = lvA.y + rvA.y + ee[1];
        float m2 = lvA.z + rvA.z + ee[2];
        float m3 = lvA.w + rvA.w + ee[3];
        m0 = (m0 > 0.f) ? m0 : 0.2f * m0;
        m1 = (m1 > 0.f) ? m1 : 0.2f * m1;
        m2 = (m2 > 0.f) ? m2 : 0.2f * m2;
        m3 = (m3 > 0.f) ? m3 : 0.2f * m3;
        p += m0 * avA.x + m1 * avA.y + m2 * avA.z + m3 * avA.w;

        ahA = ahB; alA = alB; lvA = lvB; rvA = rvB; avA = avB;
    }
    {
        f32x4 ee = (f32x4)(0.f);
        ee = __builtin_amdgcn_mfma_f32_16x16x32_bf16(ahA, bl, ee, 0, 0, 0);
        ee = __builtin_amdgcn_mfma_f32_16x16x32_bf16(alA, bh, ee, 0, 0, 0);
        ee = __builtin_amdgcn_mfma_f32_16x16x32_bf16(ahA, bh, ee, 0, 0, 0);
        float m0 = lvA.x + rvA.x + ee[0];
        float m1 = lvA.y + rvA.y + ee[1];
        float m2 = lvA.z + rvA.z + ee[2];
        float m3 = lvA.w + rvA.w + ee[3];
        m0 = (m0 > 0.f) ? m0 : 0.2f * m0;
        m1 = (m1 > 0.f) ? m1 : 0.2f * m1;
        m2 = (m2 > 0.f) ? m2 : 0.2f * m2;
        m3 = (m3 > 0.f) ? m3 : 0.2f * m3;
        p += m0 * avA.x + m1 * avA.y + m2 * avA.z + m3 * avA.w;
    }

    p += __shfl_down(p, 32, 64);
    p += __shfl_down(p, 16, 64);
    if (lane < 16)
        logits[(size_t)(e0 + lane) * H + head] = p;
}

// ---------------- fused softmax + aggregation v5: bf16 hi/lo epilogue ----------------
// Non-final layers write next layer's pre-split activations directly
// (fp32 accumulate, split at store — identical numerics to cvt_act after),
// eliminating the cvt_act read+write pass. Final layer writes fp32 for pooling.

__global__ __launch_bounds__(256) void aggregate5(
        const int* __restrict__ rowptr, const int* __restrict__ csr_src,
        const float* __restrict__ logits, const float* __restrict__ xl,
        const float* __restrict__ bias,
        short* __restrict__ outh, short* __restrict__ outl,
        float* __restrict__ outf, int last,
        int H, int co_shift, int hc, int stride) {
    __shared__ int ssrc[64];
    __shared__ float salp[64][4];
    __shared__ float sm[4], sinv[4];
    int n = blockIdx.x;
    int b = rowptr[n], t = rowptr[n + 1];
    int tid = threadIdx.x;
    int nthr = blockDim.x;

    if (tid < H) {
        float m = -1e30f;
        for (int i = b; i < t; i++)
            m = fmaxf(m, logits[(size_t)i * H + tid]);
        float s = 0.f;
        for (int i = b; i < t; i++)
            s += expf(logits[(size_t)i * H + tid] - m);
        sm[tid] = m;
        sinv[tid] = 1.f / s;    // self-loop guarantees s > 0
    }
    __syncthreads();

    int j0 = tid * 4;
    int j1 = j0 + nthr * 4;
    int h0 = j0 >> co_shift;
    int h1 = j1 >> co_shift;
    bool act1 = j1 < hc;

    float4 acc0 = make_float4(0.f, 0.f, 0.f, 0.f);
    float4 acc1 = make_float4(0.f, 0.f, 0.f, 0.f);

    for (int cb = b; cb < t; cb += 64) {
        int m = min(64, t - cb);
        __syncthreads();
        for (int i = tid; i < m; i += nthr) {
            ssrc[i] = csr_src[cb + i];
            for (int h = 0; h < H; h++)
                salp[i][h] = expf(logits[(size_t)(cb + i) * H + h] - sm[h]) * sinv[h];
        }
        __syncthreads();
        for (int i = 0; i < m; i++) {
            int s = ssrc[i];
            const float* base = xl + (size_t)s * stride;
            {
                float a = salp[i][h0];
                float4 v = *(const float4*)(base + j0);
                acc0.x += a * v.x; acc0.y += a * v.y;
                acc0.z += a * v.z; acc0.w += a * v.w;
            }
            if (act1) {
                float a = salp[i][h1];
                float4 v = *(const float4*)(base + j1);
                acc1.x += a * v.x; acc1.y += a * v.y;
                acc1.z += a * v.z; acc1.w += a * v.w;
            }
        }
    }

    float4 bz0 = *(const float4*)(bias + j0);
    float4 o0;
    o0.x = fmaxf(acc0.x + bz0.x, 0.f); o0.y = fmaxf(acc0.y + bz0.y, 0.f);
    o0.z = fmaxf(acc0.z + bz0.z, 0.f); o0.w = fmaxf(acc0.w + bz0.w, 0.f);
    if (last) {
        *(float4*)(outf + (size_t)n * hc + j0) = o0;
    } else {
        unsigned short hx = f2bf(o0.x), hy = f2bf(o0.y), hz = f2bf(o0.z), hw = f2bf(o0.w);
        short4v hv = { (short)hx, (short)hy, (short)hz, (short)hw };
        short4v lv = { (short)f2bf(o0.x - bf2f(hx)), (short)f2bf(o0.y - bf2f(hy)),
                       (short)f2bf(o0.z - bf2f(hz)), (short)f2bf(o0.w - bf2f(hw)) };
        *(short4v*)(outh + (size_t)n * hc + j0) = hv;
        *(short4v*)(outl + (size_t)n * hc + j0) = lv;
    }
    if (act1) {
        float4 bz1 = *(const float4*)(bias + j1);
        float4 o1;
        o1.x = fmaxf(acc1.x + bz1.x, 0.f); o1.y = fmaxf(acc1.y + bz1.y, 0.f);
        o1.z = fmaxf(acc1.z + bz1.z, 0.f); o1.w = fmaxf(acc1.w + bz1.w, 0.f);
        if (last) {
            *(float4*)(outf + (size_t)n * hc + j1) = o1;
        } else {
            unsigned short hx = f2bf(o1.x), hy = f2bf(o1.y), hz = f2bf(o1.z), hw = f2bf(o1.w);
            short4v hv = { (short)hx, (short)hy, (short)hz, (short)hw };
            short4v lv = { (short)f2bf(o1.x - bf2f(hx)), (short)f2bf(o1.y - bf2f(hy)),
                           (short)f2bf(o1.z - bf2f(hz)), (short)f2bf(o1.w - bf2f(hw)) };
            *(short4v*)(outh + (size_t)n * hc + j1) = hv;
            *(short4v*)(outl + (size_t)n * hc + j1) = lv;
        }
    }
}

// ---------------- pooling + MLP head ----------------

__global__ void pool_cnt(const int* __restrict__ batch, int* __restrict__ gcnt) {
    int n = blockIdx.x * 256 + threadIdx.x;
    if (n < N_NODES) atomicAdd(&gcnt[batch[n]], 1);
}

__global__ void pool_sum(const int* __restrict__ batch, const float* __restrict__ h,
                         float* __restrict__ pooled) {
    int tid = blockIdx.x * 256 + threadIdx.x;
    if (tid >= N_NODES * 256) return;
    int n = tid >> 8, c = tid & 255;
    atomicAdd(&pooled[batch[n] * 256 + c], h[tid]);
}

__global__ void mlp_head(const float* __restrict__ pooled, const int* __restrict__ gcnt,
                         const float* __restrict__ fc1w, const float* __restrict__ fc1b,
                         const float* __restrict__ fc2w, const float* __restrict__ fc2b,
                         float* __restrict__ out) {
    int g = threadIdx.x;
    if (g >= NGRAPHS) return;
    float inv = 1.f / (float)(gcnt[g] > 0 ? gcnt[g] : 1);
    float s[64];
#pragma unroll
    for (int j = 0; j < 64; j++) s[j] = fc1b[j];
    for (int c = 0; c < 256; c++) {
        float mv = pooled[g * 256 + c] * inv;
#pragma unroll
        for (int j = 0; j < 64; j++) s[j] += mv * fc1w[c * 64 + j];
    }
    float o = 0.f;
#pragma unroll
    for (int j = 0; j < 64; j++) o += fmaxf(s[j], 0.f) * fc2w[j];
    out[g] = o + fc2b[0];
}

// ---------------- launch ----------------

extern "C" void kernel_launch(void* const* d_in, const int* in_sizes, int n_in,
                              void* d_out, int out_size, void* d_ws, size_t ws_size,
                              hipStream_t stream) {
    const float* x         = (const float*)d_in[0];
    const int*   edge_index= (const int*)d_in[1];
    const float* edge_attr = (const float*)d_in[2];
    const int*   batch     = (const int*)d_in[3];
    const int* src0 = edge_index;
    const int* dst0 = edge_index + N_EDGES;

    const float *Wl[4], *bl[4], *Wr[4], *br[4], *We[4], *att[4], *bias[4];
    for (int i = 0; i < 4; i++) {
        int base = 4 + 7 * i;
        Wl[i]   = (const float*)d_in[base + 0];
        bl[i]   = (const float*)d_in[base + 1];
        Wr[i]   = (const float*)d_in[base + 2];
        br[i]   = (const float*)d_in[base + 3];
        We[i]   = (const float*)d_in[base + 4];
        att[i]  = (const float*)d_in[base + 5];
        bias[i] = (const float*)d_in[base + 6];
    }
    const float* fc1w = (const float*)d_in[32];
    const float* fc1b = (const float*)d_in[33];
    const float* fc2w = (const float*)d_in[34];
    const float* fc2b = (const float*)d_in[35];
    float* out = (float*)d_out;

    // workspace layout (float offsets) — same as round 11, presplit proven active
    float* ws = (float*)d_ws;
    int*   rowptr  = (int*)(ws + 0);            // 8001
    int*   woff    = (int*)(ws + 8064);         // 8000
    int*   eid     = (int*)(ws + 16128);        // 72000
    int*   csr_src = (int*)(ws + 88128);        // 72000
    int*   csr_dst = (int*)(ws + 160128);       // 72000
    float* ea_loop = ws + 232128;               // 8000*16
    float* ea_csr  = ws + 360128;               // 72000*16
    float* logits  = ws + 1512128;              // 72000*3
    float* xlr     = ws + 1728128;              // 8000*3072 (xl | xr fused, stride 2hc)
    float* hbF     = xlr + 24576000;            // final-layer fp32 out (8000*256 used)
    float* pooled  = hbF + 12288000;            // 16384
    int*   gcnt    = (int*)(pooled + 16384);    // 64 -> pad to 38608640
    short* wth     = (short*)(ws + 38608640);   // max 1536*2048 shorts = 1572864 floats
    short* wtl     = (short*)(ws + 40181504);   // -> ends 41754368
    short* eah     = (short*)(ws + 41754368);   // 72000*32 shorts = 1152000 floats
    short* eal     = (short*)(ws + 42906368);   // -> ends 44058368
    short* weTh    = (short*)(ws + 44058368);   // 1536*32 shorts = 24576 floats
    short* weTl    = (short*)(ws + 44082944);   // -> ends 44107520
    short* acth    = (short*)(ws + 44107520);   // 8064*1536 shorts = 6193152 floats
    short* actl    = (short*)(ws + 50300672);   // -> ends 56493824 (~226 MB, verified fits)

    hipMemsetAsync(woff, 0, N_NODES * sizeof(int), stream);
    count_deg<<<(N_EDGES + 255) / 256, 256, 0, stream>>>(dst0, woff);
    scan_deg<<<1, 256, 0, stream>>>(woff, rowptr);
    copy_off<<<(N_NODES + 255) / 256, 256, 0, stream>>>(rowptr, woff);
    fill_eid<<<(ETOT + 255) / 256, 256, 0, stream>>>(dst0, woff, eid);
    csr_fill_dst<<<(N_NODES + 255) / 256, 256, 0, stream>>>(rowptr, csr_dst);
    ea_loop_kernel<<<(N_NODES + 255) / 256, 256, 0, stream>>>(rowptr, eid, edge_attr, ea_loop);
    csr_srcea<<<(ETOT * 4 + 255) / 256, 256, 0, stream>>>(eid, src0, edge_attr, ea_loop,
                                                          csr_src, ea_csr);
    cvt_ea<<<(ETOT * EDIM + 255) / 256, 256, 0, stream>>>(ea_csr, eah, eal);
    // layer-1 input split (once; later layers' splits come from aggregate5 epilogue)
    cvt_act<<<(N_NODES * 256 / 4 + 255) / 256, 256, 0, stream>>>(x, acth, actl, N_NODES * 256);

    const int IN[4] = {256, 1536, 1024, 512};
    const int HH[4] = {3, 2, 2, 1};
    const int CO[4] = {512, 512, 256, 256};
    const int CS[4] = {9, 9, 8, 8};            // log2(co)

    for (int L = 0; L < 4; L++) {
        int K = IN[L], H = HH[L], co = CO[L], hc = H * co, cs = CS[L];
        int hc2 = 2 * hc;
        dim3 gg(hc2 / 128, (N_NODES + 127) / 128);
        dim3 gw(hc / 32, K / 32);
        cvt_wt_t<<<gw, 256, 0, stream>>>(Wl[L], wth, wtl, K, hc);
        cvt_wt_t<<<gw, 256, 0, stream>>>(Wr[L], wth + (size_t)hc * K,
                                         wtl + (size_t)hc * K, K, hc);
        gemm_mfma2<<<gg, 256, 0, stream>>>(acth, actl, wth, wtl,
                                           bl[L], br[L], hc, xlr, N_NODES, K, hc2);
        cvt_we<<<(hc + 255) / 256, 256, 0, stream>>>(We[L], weTh, weTl, hc);
        dim3 gl(ETOT / 64, H);
        edge_logits7<<<gl, 256, 0, stream>>>(
            xlr, xlr + hc, weTh, weTl, att[L], eah, eal, csr_src, csr_dst,
            logits, H, co, hc2);
        int athr = hc / 4 > 256 ? 256 : hc / 4;
        aggregate5<<<N_NODES, athr, 0, stream>>>(
            rowptr, csr_src, logits, xlr, bias[L],
            acth, actl, hbF, (L == 3) ? 1 : 0, H, cs, hc, hc2);
    }

    hipMemsetAsync(pooled, 0, (16384 + 64) * sizeof(float), stream);
    pool_cnt<<<(N_NODES + 255) / 256, 256, 0, stream>>>(batch, gcnt);
    pool_sum<<<(N_NODES * 256 + 255) / 256, 256, 0, stream>>>(batch, hbF, pooled);
    mlp_head<<<1, 64, 0, stream>>>(pooled, gcnt, fc1w, fc1b, fc2w, fc2b, out);
}

// Round 13
// 1221.158 us; speedup vs baseline: 1.0594x; 1.0594x over previous
//
#include <hip/hip_runtime.h>
#include <math.h>

#define N_NODES 8000
#define N_EDGES 64000
#define ETOT    (N_EDGES + N_NODES)   // 72000, self-loops appended
#define EDIM    16
#define NGRAPHS 64

typedef __attribute__((ext_vector_type(8))) short short8v;
typedef __attribute__((ext_vector_type(4))) short short4v;
typedef __attribute__((ext_vector_type(4))) float f32x4;

__device__ inline unsigned short f2bf(float f) {
    unsigned u = __builtin_bit_cast(unsigned, f);
    unsigned r = (u + 0x7FFF + ((u >> 16) & 1)) >> 16;   // RNE
    return (unsigned short)r;
}
__device__ inline float bf2f(unsigned short b) {
    unsigned u = ((unsigned)b) << 16;
    return __builtin_bit_cast(float, u);
}

// ---------------- CSR build ----------------

__global__ void count_deg(const int* __restrict__ dst0, int* __restrict__ deg) {
    int e = blockIdx.x * 256 + threadIdx.x;
    if (e < N_EDGES) atomicAdd(&deg[dst0[e]], 1);
}

__global__ void scan_deg(const int* __restrict__ deg, int* __restrict__ rowptr) {
    __shared__ int sh[256];
    __shared__ int carry_s;
    int t = threadIdx.x;
    if (t == 0) { carry_s = 0; rowptr[0] = 0; }
    __syncthreads();
    for (int base = 0; base < N_NODES; base += 256) {
        int i = base + t;
        int v = (i < N_NODES) ? (deg[i] + 1) : 0;   // +1 self loop
        sh[t] = v;
        __syncthreads();
        for (int off = 1; off < 256; off <<= 1) {
            int u = (t >= off) ? sh[t - off] : 0;
            __syncthreads();
            sh[t] += u;
            __syncthreads();
        }
        int incl = sh[t] + carry_s;
        if (i < N_NODES) rowptr[i + 1] = incl;
        __syncthreads();
        if (t == 255) carry_s = incl;
        __syncthreads();
    }
}

__global__ void copy_off(const int* __restrict__ rowptr, int* __restrict__ woff) {
    int i = blockIdx.x * 256 + threadIdx.x;
    if (i < N_NODES) woff[i] = rowptr[i];
}

__global__ void fill_eid(const int* __restrict__ dst0, int* __restrict__ woff,
                         int* __restrict__ eid) {
    int i = blockIdx.x * 256 + threadIdx.x;
    if (i < N_EDGES) {
        int pos = atomicAdd(&woff[dst0[i]], 1);
        eid[pos] = i;
    } else if (i < ETOT) {
        int n = i - N_EDGES;
        int pos = atomicAdd(&woff[n], 1);
        eid[pos] = i;
    }
}

__global__ void csr_fill_dst(const int* __restrict__ rowptr, int* __restrict__ csr_dst) {
    int n = blockIdx.x * 256 + threadIdx.x;
    if (n >= N_NODES) return;
    int b = rowptr[n], t = rowptr[n + 1];
    for (int i = b; i < t; i++) csr_dst[i] = n;
}

__global__ void ea_loop_kernel(const int* __restrict__ rowptr, const int* __restrict__ eid,
                               const float* __restrict__ edge_attr, float* __restrict__ ea_loop) {
    int n = blockIdx.x * 256 + threadIdx.x;
    if (n >= N_NODES) return;
    float s[EDIM];
#pragma unroll
    for (int k = 0; k < EDIM; k++) s[k] = 0.f;
    int cnt = 0;
    int b = rowptr[n], t = rowptr[n + 1];
    for (int i = b; i < t; i++) {
        int e = eid[i];
        if (e < N_EDGES) {
            cnt++;
            const float* ea = edge_attr + (size_t)e * EDIM;
#pragma unroll
            for (int k = 0; k < EDIM; k++) s[k] += ea[k];
        }
    }
    float inv = 1.f / (float)(cnt > 0 ? cnt : 1);
#pragma unroll
    for (int k = 0; k < EDIM; k++) ea_loop[(size_t)n * EDIM + k] = s[k] * inv;
}

__global__ void csr_srcea(const int* __restrict__ eid, const int* __restrict__ src0,
                          const float* __restrict__ edge_attr, const float* __restrict__ ea_loop,
                          int* __restrict__ csr_src, float* __restrict__ ea_csr) {
    int t = blockIdx.x * 256 + threadIdx.x;
    int i = t >> 2, q = t & 3;
    if (i >= ETOT) return;
    int e = eid[i];
    int s = (e < N_EDGES) ? src0[e] : (e - N_EDGES);
    if (q == 0) csr_src[i] = s;
    const float* ea = (e < N_EDGES) ? edge_attr + (size_t)e * EDIM
                                    : ea_loop + (size_t)(e - N_EDGES) * EDIM;
    *(float4*)(ea_csr + (size_t)i * EDIM + q * 4) = *(const float4*)(ea + q * 4);
}

// ea bf16 hi/lo split in MFMA B-layout rows [edge][32] (k padded 16->32 w/ zeros)
__global__ void cvt_ea(const float* __restrict__ ea_csr,
                       short* __restrict__ eah, short* __restrict__ eal) {
    int t = blockIdx.x * 256 + threadIdx.x;
    if (t >= ETOT * EDIM) return;
    int e = t >> 4, k = t & 15;
    float v = ea_csr[(size_t)e * EDIM + k];
    unsigned short h = f2bf(v);
    unsigned short l = f2bf(v - bf2f(h));
    eah[(size_t)e * 32 + k] = (short)h;
    eal[(size_t)e * 32 + k] = (short)l;
    eah[(size_t)e * 32 + 16 + k] = 0;
    eal[(size_t)e * 32 + 16 + k] = 0;
}

// We [16][hc] -> WeT hi/lo [hc][32] (A-operand layout, k padded w/ zeros)
__global__ void cvt_we(const float* __restrict__ We,
                       short* __restrict__ weTh, short* __restrict__ weTl, int hc) {
    int ch = blockIdx.x * 256 + threadIdx.x;
    if (ch >= hc) return;
#pragma unroll
    for (int k = 0; k < EDIM; k++) {
        float v = We[(size_t)k * hc + ch];
        unsigned short h = f2bf(v);
        unsigned short l = f2bf(v - bf2f(h));
        weTh[(size_t)ch * 32 + k] = (short)h;
        weTl[(size_t)ch * 32 + k] = (short)l;
    }
#pragma unroll
    for (int k = EDIM; k < 32; k++) {
        weTh[(size_t)ch * 32 + k] = 0;
        weTl[(size_t)ch * 32 + k] = 0;
    }
}

// ---------------- weight transpose + bf16 split: W[K][N] -> WT_hi/lo[N][K] ----------------

__global__ __launch_bounds__(256) void cvt_wt_t(
        const float* __restrict__ W, short* __restrict__ WTh, short* __restrict__ WTl,
        int K, int Nc) {
    __shared__ float sh[32][33];
    int t = threadIdx.x;
    int tx = t & 31, ty = t >> 5;            // 32 x 8
    int n0 = blockIdx.x * 32, k0 = blockIdx.y * 32;
#pragma unroll
    for (int j = 0; j < 4; j++)
        sh[ty + j * 8][tx] = W[(size_t)(k0 + ty + j * 8) * Nc + n0 + tx];
    __syncthreads();
#pragma unroll
    for (int j = 0; j < 4; j++) {
        int row = ty + j * 8;                 // local n
        float v = sh[tx][row];
        unsigned short h = f2bf(v);
        unsigned short l = f2bf(v - bf2f(h));
        size_t idx = (size_t)(n0 + row) * K + k0 + tx;
        WTh[idx] = (short)h;
        WTl[idx] = (short)l;
    }
}

// ---------------- activation bf16 hi/lo pre-split (layer-1 input only) ----------------

__global__ __launch_bounds__(256) void cvt_act(
        const float* __restrict__ in, short* __restrict__ acth, short* __restrict__ actl,
        int total /* M*K, multiple of 4 */) {
    int i = blockIdx.x * 256 + threadIdx.x;
    if (i * 4 >= total) return;
    float4 v = *(const float4*)(in + (size_t)i * 4);
    unsigned short h0 = f2bf(v.x), h1 = f2bf(v.y), h2 = f2bf(v.z), h3 = f2bf(v.w);
    short4v hv = { (short)h0, (short)h1, (short)h2, (short)h3 };
    short4v lv = { (short)f2bf(v.x - bf2f(h0)), (short)f2bf(v.y - bf2f(h1)),
                   (short)f2bf(v.z - bf2f(h2)), (short)f2bf(v.w - bf2f(h3)) };
    *(short4v*)(acth + (size_t)i * 4) = hv;
    *(short4v*)(actl + (size_t)i * 4) = lv;
}

// ---------------- bf16x3 MFMA GEMM, A pre-split, fused Wl|Wr (dual bias) ----------------
// Staging: coalesced (t>>1, t&1) mapping (lane pairs = 64B contiguous global
// reads — the r12 (t&127,t>>7) mapping was conflict-free but uncoalesced and
// LOST 55us). LDK=36 (18-bank row stride) makes the staging-write starts
// (18r+8s)%32 cover every even bank exactly twice (2-way = free, m136) and
// fragment-read starts 18*fr+4q all-distinct -> both phases conflict-free.

#define LDK 36   // padded LDS row stride in shorts (32 + 4)

__global__ __launch_bounds__(256) void gemm_mfma2(
        const short* __restrict__ Ah_g, const short* __restrict__ Al_g,
        const short* __restrict__ BTh, const short* __restrict__ BTl,
        const float* __restrict__ bias1, const float* __restrict__ bias2, int hsplit,
        float* __restrict__ C, int M, int K, int Nc) {
    __shared__ short Ah[128 * LDK];
    __shared__ short Al[128 * LDK];
    __shared__ short Bh[128 * LDK];
    __shared__ short Bl[128 * LDK];
    int t = threadIdx.x;
    int m0 = blockIdx.y * 128, n0 = blockIdx.x * 128;
    int lane = t & 63, wave = t >> 6;
    int wm = (wave >> 1) * 64, wn = (wave & 1) * 64;
    int fr = lane & 15, koff = (lane >> 4) * 8;

    f32x4 acc[4][4];
#pragma unroll
    for (int i = 0; i < 4; i++)
#pragma unroll
        for (int j = 0; j < 4; j++) acc[i][j] = (f32x4)(0.f);

    int srow = t >> 1, sseg = t & 1;          // coalesced staging mapping

    for (int k0 = 0; k0 < K; k0 += 32) {
        __syncthreads();
        {
            const short* ga_h = Ah_g + (size_t)(m0 + srow) * K + k0 + sseg * 16;
            const short* ga_l = Al_g + (size_t)(m0 + srow) * K + k0 + sseg * 16;
            const short* gb_h = BTh + (size_t)(n0 + srow) * K + k0 + sseg * 16;
            const short* gb_l = BTl + (size_t)(n0 + srow) * K + k0 + sseg * 16;
            int lo = srow * LDK + sseg * 16;
            *(short8v*)&Ah[lo]     = *(const short8v*)ga_h;
            *(short8v*)&Ah[lo + 8] = *(const short8v*)(ga_h + 8);
            *(short8v*)&Al[lo]     = *(const short8v*)ga_l;
            *(short8v*)&Al[lo + 8] = *(const short8v*)(ga_l + 8);
            *(short8v*)&Bh[lo]     = *(const short8v*)gb_h;
            *(short8v*)&Bh[lo + 8] = *(const short8v*)(gb_h + 8);
            *(short8v*)&Bl[lo]     = *(const short8v*)gb_l;
            *(short8v*)&Bl[lo + 8] = *(const short8v*)(gb_l + 8);
        }
        __syncthreads();

        short8v ah[4], al[4], bh[4], bl[4];
#pragma unroll
        for (int mi = 0; mi < 4; mi++) {
            int r = (wm + mi * 16 + fr) * LDK + koff;
            ah[mi] = *(short8v*)&Ah[r];
            al[mi] = *(short8v*)&Al[r];
        }
#pragma unroll
        for (int ni = 0; ni < 4; ni++) {
            int r = (wn + ni * 16 + fr) * LDK + koff;
            bh[ni] = *(short8v*)&Bh[r];
            bl[ni] = *(short8v*)&Bl[r];
        }
#pragma unroll
        for (int mi = 0; mi < 4; mi++)
#pragma unroll
            for (int ni = 0; ni < 4; ni++) {
                acc[mi][ni] = __builtin_amdgcn_mfma_f32_16x16x32_bf16(
                    al[mi], bh[ni], acc[mi][ni], 0, 0, 0);
                acc[mi][ni] = __builtin_amdgcn_mfma_f32_16x16x32_bf16(
                    ah[mi], bl[ni], acc[mi][ni], 0, 0, 0);
                acc[mi][ni] = __builtin_amdgcn_mfma_f32_16x16x32_bf16(
                    ah[mi], bh[ni], acc[mi][ni], 0, 0, 0);
            }
    }

    int rbase = (lane >> 4) * 4;
#pragma unroll
    for (int ni = 0; ni < 4; ni++) {
        int col = n0 + wn + ni * 16 + fr;
        const float* bp = (col < hsplit) ? bias1 + col : bias2 + (col - hsplit);
        float bz = *bp;
#pragma unroll
        for (int mi = 0; mi < 4; mi++) {
            int row0 = m0 + wm + mi * 16 + rbase;
#pragma unroll
            for (int r = 0; r < 4; r++) {
                int row = row0 + r;
                if (row < M) C[(size_t)row * Nc + col] = acc[mi][ni][r] + bz;
            }
        }
    }
}

// ---------------- edge logits v7: MFMA ee, per-head block, 2-deep pipeline ----------------

__global__ __launch_bounds__(256, 4) void edge_logits7(
        const float* __restrict__ xl, const float* __restrict__ xr,
        const short* __restrict__ weTh, const short* __restrict__ weTl,
        const float* __restrict__ att,
        const short* __restrict__ eah, const short* __restrict__ eal,
        const int* __restrict__ csr_src, const int* __restrict__ csr_dst,
        float* __restrict__ logits, int H, int co, int stride) {
    int tid = threadIdx.x;
    int lane = tid & 63, wave = tid >> 6;
    int head = blockIdx.y;
    int cbase = head * co;
    int e0 = blockIdx.x * 64 + wave * 16;    // ETOT % 64 == 0
    int col = lane & 15;                     // edge within tile
    int quad = lane >> 4;
    int e = e0 + col;
    int s = csr_src[e], d = csr_dst[e];
    int ch0 = cbase + quad * 4;

    short8v bh = *(const short8v*)(eah + (size_t)e * 32 + quad * 8);
    short8v bl = *(const short8v*)(eal + (size_t)e * 32 + quad * 8);

    const float* xls = xl + (size_t)s * stride + ch0;
    const float* xrd = xr + (size_t)d * stride + ch0;
    const float* atp = att + ch0;
    const short* wph = weTh + (size_t)(cbase + col) * 32 + quad * 8;
    const short* wpl = weTl + (size_t)(cbase + col) * 32 + quad * 8;

    int ntile = co >> 4;
    float p = 0.f;

    short8v ahA = *(const short8v*)wph;
    short8v alA = *(const short8v*)wpl;
    float4 lvA = *(const float4*)xls;
    float4 rvA = *(const float4*)xrd;
    float4 avA = *(const float4*)atp;

    for (int tt = 0; tt < ntile - 1; tt++) {
        short8v ahB = *(const short8v*)(wph + (size_t)(tt + 1) * 512);
        short8v alB = *(const short8v*)(wpl + (size_t)(tt + 1) * 512);
        float4 lvB = *(const float4*)(xls + (tt + 1) * 16);
        float4 rvB = *(const float4*)(xrd + (tt + 1) * 16);
        float4 avB = *(const float4*)(atp + (tt + 1) * 16);

        f32x4 ee = (f32x4)(0.f);
        ee = __builtin_amdgcn_mfma_f32_16x16x32_bf16(ahA, bl, ee, 0, 0, 0);
        ee = __builtin_amdgcn_mfma_f32_16x16x32_bf16(alA, bh, ee, 0, 0, 0);
        ee = __builtin_amdgcn_mfma_f32_16x16x32_bf16(ahA, bh, ee, 0, 0, 0);
        float m0 = lvA.x + rvA.x + ee[0];
        float m1 = lvA.y + rvA.y + ee[1];
        float m2 = lvA.z + rvA.z + ee[2];
        float m3 = lvA.w + rvA.w + ee[3];
        m0 = (m0 > 0.f) ? m0 : 0.2f * m0;
        m1 = (m1 > 0.f) ? m1 : 0.2f * m1;
        m2 = (m2 > 0.f) ? m2 : 0.2f * m2;
        m3 = (m3 > 0.f) ? m3 : 0.2f * m3;
        p += m0 * avA.x + m1 * avA.y + m2 * avA.z + m3 * avA.w;

        ahA = ahB; alA = alB; lvA = lvB; rvA = rvB; avA = avB;
    }
    {
        f32x4 ee = (f32x4)(0.f);
        ee = __builtin_amdgcn_mfma_f32_16x16x32_bf16(ahA, bl, ee, 0, 0, 0);
        ee = __builtin_amdgcn_mfma_f32_16x16x32_bf16(alA, bh, ee, 0, 0, 0);
        ee = __builtin_amdgcn_mfma_f32_16x16x32_bf16(ahA, bh, ee, 0, 0, 0);
        float m0 = lvA.x + rvA.x + ee[0];
        float m1 = lvA.y + rvA.y + ee[1];
        float m2 = lvA.z + rvA.z + ee[2];
        float m3 = lvA.w + rvA.w + ee[3];
        m0 = (m0 > 0.f) ? m0 : 0.2f * m0;
        m1 = (m1 > 0.f) ? m1 : 0.2f * m1;
        m2 = (m2 > 0.f) ? m2 : 0.2f * m2;
        m3 = (m3 > 0.f) ? m3 : 0.2f * m3;
        p += m0 * avA.x + m1 * avA.y + m2 * avA.z + m3 * avA.w;
    }

    p += __shfl_down(p, 32, 64);
    p += __shfl_down(p, 16, 64);
    if (lane < 16)
        logits[(size_t)(e0 + lane) * H + head] = p;
}

// ---------------- fused softmax + aggregation v5: bf16 hi/lo epilogue ----------------

__global__ __launch_bounds__(256) void aggregate5(
        const int* __restrict__ rowptr, const int* __restrict__ csr_src,
        const float* __restrict__ logits, const float* __restrict__ xl,
        const float* __restrict__ bias,
        short* __restrict__ outh, short* __restrict__ outl,
        float* __restrict__ outf, int last,
        int H, int co_shift, int hc, int stride) {
    __shared__ int ssrc[64];
    __shared__ float salp[64][4];
    __shared__ float sm[4], sinv[4];
    int n = blockIdx.x;
    int b = rowptr[n], t = rowptr[n + 1];
    int tid = threadIdx.x;
    int nthr = blockDim.x;

    if (tid < H) {
        float m = -1e30f;
        for (int i = b; i < t; i++)
            m = fmaxf(m, logits[(size_t)i * H + tid]);
        float s = 0.f;
        for (int i = b; i < t; i++)
            s += expf(logits[(size_t)i * H + tid] - m);
        sm[tid] = m;
        sinv[tid] = 1.f / s;    // self-loop guarantees s > 0
    }
    __syncthreads();

    int j0 = tid * 4;
    int j1 = j0 + nthr * 4;
    int h0 = j0 >> co_shift;
    int h1 = j1 >> co_shift;
    bool act1 = j1 < hc;

    float4 acc0 = make_float4(0.f, 0.f, 0.f, 0.f);
    float4 acc1 = make_float4(0.f, 0.f, 0.f, 0.f);

    for (int cb = b; cb < t; cb += 64) {
        int m = min(64, t - cb);
        __syncthreads();
        for (int i = tid; i < m; i += nthr) {
            ssrc[i] = csr_src[cb + i];
            for (int h = 0; h < H; h++)
                salp[i][h] = expf(logits[(size_t)(cb + i) * H + h] - sm[h]) * sinv[h];
        }
        __syncthreads();
        for (int i = 0; i < m; i++) {
            int s = ssrc[i];
            const float* base = xl + (size_t)s * stride;
            {
                float a = salp[i][h0];
                float4 v = *(const float4*)(base + j0);
                acc0.x += a * v.x; acc0.y += a * v.y;
                acc0.z += a * v.z; acc0.w += a * v.w;
            }
            if (act1) {
                float a = salp[i][h1];
                float4 v = *(const float4*)(base + j1);
                acc1.x += a * v.x; acc1.y += a * v.y;
                acc1.z += a * v.z; acc1.w += a * v.w;
            }
        }
    }

    float4 bz0 = *(const float4*)(bias + j0);
    float4 o0;
    o0.x = fmaxf(acc0.x + bz0.x, 0.f); o0.y = fmaxf(acc0.y + bz0.y, 0.f);
    o0.z = fmaxf(acc0.z + bz0.z, 0.f); o0.w = fmaxf(acc0.w + bz0.w, 0.f);
    if (last) {
        *(float4*)(outf + (size_t)n * hc + j0) = o0;
    } else {
        unsigned short hx = f2bf(o0.x), hy = f2bf(o0.y), hz = f2bf(o0.z), hw = f2bf(o0.w);
        short4v hv = { (short)hx, (short)hy, (short)hz, (short)hw };
        short4v lv = { (short)f2bf(o0.x - bf2f(hx)), (short)f2bf(o0.y - bf2f(hy)),
                       (short)f2bf(o0.z - bf2f(hz)), (short)f2bf(o0.w - bf2f(hw)) };
        *(short4v*)(outh + (size_t)n * hc + j0) = hv;
        *(short4v*)(outl + (size_t)n * hc + j0) = lv;
    }
    if (act1) {
        float4 bz1 = *(const float4*)(bias + j1);
        float4 o1;
        o1.x = fmaxf(acc1.x + bz1.x, 0.f); o1.y = fmaxf(acc1.y + bz1.y, 0.f);
        o1.z = fmaxf(acc1.z + bz1.z, 0.f); o1.w = fmaxf(acc1.w + bz1.w, 0.f);
        if (last) {
            *(float4*)(outf + (size_t)n * hc + j1) = o1;
        } else {
            unsigned short hx = f2bf(o1.x), hy = f2bf(o1.y), hz = f2bf(o1.z), hw = f2bf(o1.w);
            short4v hv = { (short)hx, (short)hy, (short)hz, (short)hw };
            short4v lv = { (short)f2bf(o1.x - bf2f(hx)), (short)f2bf(o1.y - bf2f(hy)),
                           (short)f2bf(o1.z - bf2f(hz)), (short)f2bf(o1.w - bf2f(hw)) };
            *(short4v*)(outh + (size_t)n * hc + j1) = hv;
            *(short4v*)(outl + (size_t)n * hc + j1) = lv;
        }
    }
}

// ---------------- pooling + MLP head ----------------

__global__ void pool_cnt(const int* __restrict__ batch, int* __restrict__ gcnt) {
    int n = blockIdx.x * 256 + threadIdx.x;
    if (n < N_NODES) atomicAdd(&gcnt[batch[n]], 1);
}

__global__ void pool_sum(const int* __restrict__ batch, const float* __restrict__ h,
                         float* __restrict__ pooled) {
    int tid = blockIdx.x * 256 + threadIdx.x;
    if (tid >= N_NODES * 256) return;
    int n = tid >> 8, c = tid & 255;
    atomicAdd(&pooled[batch[n] * 256 + c], h[tid]);
}

__global__ void mlp_head(const float* __restrict__ pooled, const int* __restrict__ gcnt,
                         const float* __restrict__ fc1w, const float* __restrict__ fc1b,
                         const float* __restrict__ fc2w, const float* __restrict__ fc2b,
                         float* __restrict__ out) {
    int g = threadIdx.x;
    if (g >= NGRAPHS) return;
    float inv = 1.f / (float)(gcnt[g] > 0 ? gcnt[g] : 1);
    float s[64];
#pragma unroll
    for (int j = 0; j < 64; j++) s[j] = fc1b[j];
    for (int c = 0; c < 256; c++) {
        float mv = pooled[g * 256 + c] * inv;
#pragma unroll
        for (int j = 0; j < 64; j++) s[j] += mv * fc1w[c * 64 + j];
    }
    float o = 0.f;
#pragma unroll
    for (int j = 0; j < 64; j++) o += fmaxf(s[j], 0.f) * fc2w[j];
    out[g] = o + fc2b[0];
}

// ---------------- launch ----------------

extern "C" void kernel_launch(void* const* d_in, const int* in_sizes, int n_in,
                              void* d_out, int out_size, void* d_ws, size_t ws_size,
                              hipStream_t stream) {
    const float* x         = (const float*)d_in[0];
    const int*   edge_index= (const int*)d_in[1];
    const float* edge_attr = (const float*)d_in[2];
    const int*   batch     = (const int*)d_in[3];
    const int* src0 = edge_index;
    const int* dst0 = edge_index + N_EDGES;

    const float *Wl[4], *bl[4], *Wr[4], *br[4], *We[4], *att[4], *bias[4];
    for (int i = 0; i < 4; i++) {
        int base = 4 + 7 * i;
        Wl[i]   = (const float*)d_in[base + 0];
        bl[i]   = (const float*)d_in[base + 1];
        Wr[i]   = (const float*)d_in[base + 2];
        br[i]   = (const float*)d_in[base + 3];
        We[i]   = (const float*)d_in[base + 4];
        att[i]  = (const float*)d_in[base + 5];
        bias[i] = (const float*)d_in[base + 6];
    }
    const float* fc1w = (const float*)d_in[32];
    const float* fc1b = (const float*)d_in[33];
    const float* fc2w = (const float*)d_in[34];
    const float* fc2b = (const float*)d_in[35];
    float* out = (float*)d_out;

    // workspace layout (float offsets)
    float* ws = (float*)d_ws;
    int*   rowptr  = (int*)(ws + 0);            // 8001
    int*   woff    = (int*)(ws + 8064);         // 8000
    int*   eid     = (int*)(ws + 16128);        // 72000
    int*   csr_src = (int*)(ws + 88128);        // 72000
    int*   csr_dst = (int*)(ws + 160128);       // 72000
    float* ea_loop = ws + 232128;               // 8000*16
    float* ea_csr  = ws + 360128;               // 72000*16
    float* logits  = ws + 1512128;              // 72000*3
    float* xlr     = ws + 1728128;              // 8000*3072 (xl | xr fused, stride 2hc)
    float* hbF     = xlr + 24576000;            // final-layer fp32 out (8000*256 used)
    float* pooled  = hbF + 12288000;            // 16384
    int*   gcnt    = (int*)(pooled + 16384);    // 64 -> pad to 38608640
    short* wth     = (short*)(ws + 38608640);   // max 1536*2048 shorts = 1572864 floats
    short* wtl     = (short*)(ws + 40181504);   // -> ends 41754368
    short* eah     = (short*)(ws + 41754368);   // 72000*32 shorts = 1152000 floats
    short* eal     = (short*)(ws + 42906368);   // -> ends 44058368
    short* weTh    = (short*)(ws + 44058368);   // 1536*32 shorts = 24576 floats
    short* weTl    = (short*)(ws + 44082944);   // -> ends 44107520
    short* acth    = (short*)(ws + 44107520);   // 8064*1536 shorts = 6193152 floats
    short* actl    = (short*)(ws + 50300672);   // -> ends 56493824 (~226 MB, verified fits)

    hipMemsetAsync(woff, 0, N_NODES * sizeof(int), stream);
    count_deg<<<(N_EDGES + 255) / 256, 256, 0, stream>>>(dst0, woff);
    scan_deg<<<1, 256, 0, stream>>>(woff, rowptr);
    copy_off<<<(N_NODES + 255) / 256, 256, 0, stream>>>(rowptr, woff);
    fill_eid<<<(ETOT + 255) / 256, 256, 0, stream>>>(dst0, woff, eid);
    csr_fill_dst<<<(N_NODES + 255) / 256, 256, 0, stream>>>(rowptr, csr_dst);
    ea_loop_kernel<<<(N_NODES + 255) / 256, 256, 0, stream>>>(rowptr, eid, edge_attr, ea_loop);
    csr_srcea<<<(ETOT * 4 + 255) / 256, 256, 0, stream>>>(eid, src0, edge_attr, ea_loop,
                                                          csr_src, ea_csr);
    cvt_ea<<<(ETOT * EDIM + 255) / 256, 256, 0, stream>>>(ea_csr, eah, eal);
    // layer-1 input split (once; later layers' splits come from aggregate5 epilogue)
    cvt_act<<<(N_NODES * 256 / 4 + 255) / 256, 256, 0, stream>>>(x, acth, actl, N_NODES * 256);

    const int IN[4] = {256, 1536, 1024, 512};
    const int HH[4] = {3, 2, 2, 1};
    const int CO[4] = {512, 512, 256, 256};
    const int CS[4] = {9, 9, 8, 8};            // log2(co)

    for (int L = 0; L < 4; L++) {
        int K = IN[L], H = HH[L], co = CO[L], hc = H * co, cs = CS[L];
        int hc2 = 2 * hc;
        dim3 gg(hc2 / 128, (N_NODES + 127) / 128);
        dim3 gw(hc / 32, K / 32);
        cvt_wt_t<<<gw, 256, 0, stream>>>(Wl[L], wth, wtl, K, hc);
        cvt_wt_t<<<gw, 256, 0, stream>>>(Wr[L], wth + (size_t)hc * K,
                                         wtl + (size_t)hc * K, K, hc);
        gemm_mfma2<<<gg, 256, 0, stream>>>(acth, actl, wth, wtl,
                                           bl[L], br[L], hc, xlr, N_NODES, K, hc2);
        cvt_we<<<(hc + 255) / 256, 256, 0, stream>>>(We[L], weTh, weTl, hc);
        dim3 gl(ETOT / 64, H);
        edge_logits7<<<gl, 256, 0, stream>>>(
            xlr, xlr + hc, weTh, weTl, att[L], eah, eal, csr_src, csr_dst,
            logits, H, co, hc2);
        int athr = hc / 4 > 256 ? 256 : hc / 4;
        aggregate5<<<N_NODES, athr, 0, stream>>>(
            rowptr, csr_src, logits, xlr, bias[L],
            acth, actl, hbF, (L == 3) ? 1 : 0, H, cs, hc, hc2);
    }

    hipMemsetAsync(pooled, 0, (16384 + 64) * sizeof(float), stream);
    pool_cnt<<<(N_NODES + 255) / 256, 256, 0, stream>>>(batch, gcnt);
    pool_sum<<<(N_NODES * 256 + 255) / 256, 256, 0, stream>>>(batch, hbF, pooled);
    mlp_head<<<1, 64, 0, stream>>>(pooled, gcnt, fc1w, fc1b, fc2w, fc2b, out);
}

// Round 14
// 1189.379 us; speedup vs baseline: 1.0877x; 1.0267x over previous
//
#include <hip/hip_runtime.h>
#include <math.h>

#define N_NODES 8000
#define N_EDGES 64000
#define ETOT    (N_EDGES + N_NODES)   // 72000, self-loops appended
#define EDIM    16
#define NGRAPHS 64

typedef __attribute__((ext_vector_type(8))) short short8v;
typedef __attribute__((ext_vector_type(4))) short short4v;
typedef __attribute__((ext_vector_type(4))) float f32x4;

__device__ inline unsigned short f2bf(float f) {
    unsigned u = __builtin_bit_cast(unsigned, f);
    unsigned r = (u + 0x7FFF + ((u >> 16) & 1)) >> 16;   // RNE
    return (unsigned short)r;
}
__device__ inline float bf2f(unsigned short b) {
    unsigned u = ((unsigned)b) << 16;
    return __builtin_bit_cast(float, u);
}

// ---------------- CSR build ----------------

__global__ void count_deg(const int* __restrict__ dst0, int* __restrict__ deg) {
    int e = blockIdx.x * 256 + threadIdx.x;
    if (e < N_EDGES) atomicAdd(&deg[dst0[e]], 1);
}

// efficient single-block scan: 256 threads x 32 serial + one 256 block-scan.
// emits rowptr (inclusive, +self-loop) AND woff (exclusive) in one pass.
__global__ void scan_deg2(const int* __restrict__ deg, int* __restrict__ rowptr,
                          int* __restrict__ woff) {
    __shared__ int stot[256];
    int t = threadIdx.x;
    int base = t * 32;
    int sum = 0;
    for (int j = 0; j < 32; j++) {
        int i = base + j;
        if (i < N_NODES) sum += deg[i] + 1;
    }
    stot[t] = sum;
    __syncthreads();
    for (int off = 1; off < 256; off <<= 1) {
        int u = (t >= off) ? stot[t - off] : 0;
        __syncthreads();
        stot[t] += u;
        __syncthreads();
    }
    int run = (t == 0) ? 0 : stot[t - 1];
    if (t == 0) rowptr[0] = 0;
    for (int j = 0; j < 32; j++) {
        int i = base + j;
        if (i < N_NODES) {
            int v = deg[i] + 1;
            woff[i] = run;
            rowptr[i + 1] = run + v;
            run += v;
        }
    }
}

__global__ void fill_eid(const int* __restrict__ dst0, int* __restrict__ woff,
                         int* __restrict__ eid) {
    int i = blockIdx.x * 256 + threadIdx.x;
    if (i < N_EDGES) {
        int pos = atomicAdd(&woff[dst0[i]], 1);
        eid[pos] = i;
    } else if (i < ETOT) {
        int n = i - N_EDGES;
        int pos = atomicAdd(&woff[n], 1);
        eid[pos] = i;
    }
}

__global__ void csr_fill_dst(const int* __restrict__ rowptr, int* __restrict__ csr_dst) {
    int n = blockIdx.x * 256 + threadIdx.x;
    if (n >= N_NODES) return;
    int b = rowptr[n], t = rowptr[n + 1];
    for (int i = b; i < t; i++) csr_dst[i] = n;
}

__global__ void ea_loop_kernel(const int* __restrict__ rowptr, const int* __restrict__ eid,
                               const float* __restrict__ edge_attr, float* __restrict__ ea_loop) {
    int n = blockIdx.x * 256 + threadIdx.x;
    if (n >= N_NODES) return;
    float s[EDIM];
#pragma unroll
    for (int k = 0; k < EDIM; k++) s[k] = 0.f;
    int cnt = 0;
    int b = rowptr[n], t = rowptr[n + 1];
    for (int i = b; i < t; i++) {
        int e = eid[i];
        if (e < N_EDGES) {
            cnt++;
            const float* ea = edge_attr + (size_t)e * EDIM;
#pragma unroll
            for (int k = 0; k < EDIM; k++) s[k] += ea[k];
        }
    }
    float inv = 1.f / (float)(cnt > 0 ? cnt : 1);
#pragma unroll
    for (int k = 0; k < EDIM; k++) ea_loop[(size_t)n * EDIM + k] = s[k] * inv;
}

// csr_src + ea bf16 hi/lo split (MFMA B-layout [edge][32], k padded w/ zeros),
// fused: reads edge_attr/ea_loop via eid, emits eah/eal directly (no fp32 copy).
__global__ void csr_srcea_bf(const int* __restrict__ eid, const int* __restrict__ src0,
                             const float* __restrict__ edge_attr, const float* __restrict__ ea_loop,
                             int* __restrict__ csr_src,
                             short* __restrict__ eah, short* __restrict__ eal) {
    int t = blockIdx.x * 256 + threadIdx.x;
    int i = t >> 2, q = t & 3;
    if (i >= ETOT) return;
    int e = eid[i];
    int s = (e < N_EDGES) ? src0[e] : (e - N_EDGES);
    if (q == 0) csr_src[i] = s;
    const float* ea = (e < N_EDGES) ? edge_attr + (size_t)e * EDIM
                                    : ea_loop + (size_t)(e - N_EDGES) * EDIM;
    float4 v = *(const float4*)(ea + q * 4);
    unsigned short h0 = f2bf(v.x), h1 = f2bf(v.y), h2 = f2bf(v.z), h3 = f2bf(v.w);
    short4v hv = { (short)h0, (short)h1, (short)h2, (short)h3 };
    short4v lv = { (short)f2bf(v.x - bf2f(h0)), (short)f2bf(v.y - bf2f(h1)),
                   (short)f2bf(v.z - bf2f(h2)), (short)f2bf(v.w - bf2f(h3)) };
    short4v zv = { 0, 0, 0, 0 };
    *(short4v*)(eah + (size_t)i * 32 + q * 4) = hv;
    *(short4v*)(eal + (size_t)i * 32 + q * 4) = lv;
    *(short4v*)(eah + (size_t)i * 32 + 16 + q * 4) = zv;
    *(short4v*)(eal + (size_t)i * 32 + 16 + q * 4) = zv;
}

// All 4 layers' We -> WeT hi/lo [ch][32] in one launch (channel-flattened).
__global__ void cvt_we_all(const float* __restrict__ We1, const float* __restrict__ We2,
                           const float* __restrict__ We3, const float* __restrict__ We4,
                           short* __restrict__ weTh, short* __restrict__ weTl) {
    int ch = blockIdx.x * 256 + threadIdx.x;
    if (ch >= 3328) return;                  // 1536 + 1024 + 512 + 256
    const float* We; int lch, hc;
    if (ch < 1536)      { We = We1; lch = ch;        hc = 1536; }
    else if (ch < 2560) { We = We2; lch = ch - 1536; hc = 1024; }
    else if (ch < 3072) { We = We3; lch = ch - 2560; hc = 512;  }
    else                { We = We4; lch = ch - 3072; hc = 256;  }
#pragma unroll
    for (int k = 0; k < EDIM; k++) {
        float v = We[(size_t)k * hc + lch];
        unsigned short h = f2bf(v);
        unsigned short l = f2bf(v - bf2f(h));
        weTh[(size_t)ch * 32 + k] = (short)h;
        weTl[(size_t)ch * 32 + k] = (short)l;
    }
#pragma unroll
    for (int k = EDIM; k < 32; k++) {
        weTh[(size_t)ch * 32 + k] = 0;
        weTl[(size_t)ch * 32 + k] = 0;
    }
}

// ---------------- weight transpose + bf16 split, Wl & Wr in one launch (z) ----------------

__global__ __launch_bounds__(256) void cvt_wt_t2(
        const float* __restrict__ Wl, const float* __restrict__ Wr,
        short* __restrict__ WTh, short* __restrict__ WTl, int K, int Nc) {
    __shared__ float sh[32][33];
    const float* W = blockIdx.z ? Wr : Wl;
    size_t obase = blockIdx.z ? (size_t)Nc * K : 0;
    int t = threadIdx.x;
    int tx = t & 31, ty = t >> 5;            // 32 x 8
    int n0 = blockIdx.x * 32, k0 = blockIdx.y * 32;
#pragma unroll
    for (int j = 0; j < 4; j++)
        sh[ty + j * 8][tx] = W[(size_t)(k0 + ty + j * 8) * Nc + n0 + tx];
    __syncthreads();
#pragma unroll
    for (int j = 0; j < 4; j++) {
        int row = ty + j * 8;                 // local n
        float v = sh[tx][row];
        unsigned short h = f2bf(v);
        unsigned short l = f2bf(v - bf2f(h));
        size_t idx = obase + (size_t)(n0 + row) * K + k0 + tx;
        WTh[idx] = (short)h;
        WTl[idx] = (short)l;
    }
}

// ---------------- activation bf16 hi/lo pre-split (layer-1 input only) ----------------

__global__ __launch_bounds__(256) void cvt_act(
        const float* __restrict__ in, short* __restrict__ acth, short* __restrict__ actl,
        int total /* M*K, multiple of 4 */) {
    int i = blockIdx.x * 256 + threadIdx.x;
    if (i * 4 >= total) return;
    float4 v = *(const float4*)(in + (size_t)i * 4);
    unsigned short h0 = f2bf(v.x), h1 = f2bf(v.y), h2 = f2bf(v.z), h3 = f2bf(v.w);
    short4v hv = { (short)h0, (short)h1, (short)h2, (short)h3 };
    short4v lv = { (short)f2bf(v.x - bf2f(h0)), (short)f2bf(v.y - bf2f(h1)),
                   (short)f2bf(v.z - bf2f(h2)), (short)f2bf(v.w - bf2f(h3)) };
    *(short4v*)(acth + (size_t)i * 4) = hv;
    *(short4v*)(actl + (size_t)i * 4) = lv;
}

// ---------------- bf16x3 MFMA GEMM, A pre-split, fused Wl|Wr (dual bias) ----------------
// Coalesced (t>>1, t&1) staging (64B contiguous per lane pair). LDK=36.
// Residual SQ_LDS_BANK_CONFLICT (~1.2e7) is inherent 2-way wave64 aliasing
// (free per m136) — halving it r11->r13 moved dur by only ~2us.

#define LDK 36   // padded LDS row stride in shorts (32 + 4)

__global__ __launch_bounds__(256) void gemm_mfma2(
        const short* __restrict__ Ah_g, const short* __restrict__ Al_g,
        const short* __restrict__ BTh, const short* __restrict__ BTl,
        const float* __restrict__ bias1, const float* __restrict__ bias2, int hsplit,
        float* __restrict__ C, int M, int K, int Nc) {
    __shared__ short Ah[128 * LDK];
    __shared__ short Al[128 * LDK];
    __shared__ short Bh[128 * LDK];
    __shared__ short Bl[128 * LDK];
    int t = threadIdx.x;
    int m0 = blockIdx.y * 128, n0 = blockIdx.x * 128;
    int lane = t & 63, wave = t >> 6;
    int wm = (wave >> 1) * 64, wn = (wave & 1) * 64;
    int fr = lane & 15, koff = (lane >> 4) * 8;

    f32x4 acc[4][4];
#pragma unroll
    for (int i = 0; i < 4; i++)
#pragma unroll
        for (int j = 0; j < 4; j++) acc[i][j] = (f32x4)(0.f);

    int srow = t >> 1, sseg = t & 1;          // coalesced staging mapping

    for (int k0 = 0; k0 < K; k0 += 32) {
        __syncthreads();
        {
            const short* ga_h = Ah_g + (size_t)(m0 + srow) * K + k0 + sseg * 16;
            const short* ga_l = Al_g + (size_t)(m0 + srow) * K + k0 + sseg * 16;
            const short* gb_h = BTh + (size_t)(n0 + srow) * K + k0 + sseg * 16;
            const short* gb_l = BTl + (size_t)(n0 + srow) * K + k0 + sseg * 16;
            int lo = srow * LDK + sseg * 16;
            *(short8v*)&Ah[lo]     = *(const short8v*)ga_h;
            *(short8v*)&Ah[lo + 8] = *(const short8v*)(ga_h + 8);
            *(short8v*)&Al[lo]     = *(const short8v*)ga_l;
            *(short8v*)&Al[lo + 8] = *(const short8v*)(ga_l + 8);
            *(short8v*)&Bh[lo]     = *(const short8v*)gb_h;
            *(short8v*)&Bh[lo + 8] = *(const short8v*)(gb_h + 8);
            *(short8v*)&Bl[lo]     = *(const short8v*)gb_l;
            *(short8v*)&Bl[lo + 8] = *(const short8v*)(gb_l + 8);
        }
        __syncthreads();

        short8v ah[4], al[4], bh[4], bl[4];
#pragma unroll
        for (int mi = 0; mi < 4; mi++) {
            int r = (wm + mi * 16 + fr) * LDK + koff;
            ah[mi] = *(short8v*)&Ah[r];
            al[mi] = *(short8v*)&Al[r];
        }
#pragma unroll
        for (int ni = 0; ni < 4; ni++) {
            int r = (wn + ni * 16 + fr) * LDK + koff;
            bh[ni] = *(short8v*)&Bh[r];
            bl[ni] = *(short8v*)&Bl[r];
        }
#pragma unroll
        for (int mi = 0; mi < 4; mi++)
#pragma unroll
            for (int ni = 0; ni < 4; ni++) {
                acc[mi][ni] = __builtin_amdgcn_mfma_f32_16x16x32_bf16(
                    al[mi], bh[ni], acc[mi][ni], 0, 0, 0);
                acc[mi][ni] = __builtin_amdgcn_mfma_f32_16x16x32_bf16(
                    ah[mi], bl[ni], acc[mi][ni], 0, 0, 0);
                acc[mi][ni] = __builtin_amdgcn_mfma_f32_16x16x32_bf16(
                    ah[mi], bh[ni], acc[mi][ni], 0, 0, 0);
            }
    }

    int rbase = (lane >> 4) * 4;
#pragma unroll
    for (int ni = 0; ni < 4; ni++) {
        int col = n0 + wn + ni * 16 + fr;
        const float* bp = (col < hsplit) ? bias1 + col : bias2 + (col - hsplit);
        float bz = *bp;
#pragma unroll
        for (int mi = 0; mi < 4; mi++) {
            int row0 = m0 + wm + mi * 16 + rbase;
#pragma unroll
            for (int r = 0; r < 4; r++) {
                int row = row0 + r;
                if (row < M) C[(size_t)row * Nc + col] = acc[mi][ni][r] + bz;
            }
        }
    }
}

// ---------------- edge logits v7: MFMA ee, per-head block, 2-deep pipeline ----------------

__global__ __launch_bounds__(256, 4) void edge_logits7(
        const float* __restrict__ xl, const float* __restrict__ xr,
        const short* __restrict__ weTh, const short* __restrict__ weTl,
        const float* __restrict__ att,
        const short* __restrict__ eah, const short* __restrict__ eal,
        const int* __restrict__ csr_src, const int* __restrict__ csr_dst,
        float* __restrict__ logits, int H, int co, int stride) {
    int tid = threadIdx.x;
    int lane = tid & 63, wave = tid >> 6;
    int head = blockIdx.y;
    int cbase = head * co;
    int e0 = blockIdx.x * 64 + wave * 16;    // ETOT % 64 == 0
    int col = lane & 15;                     // edge within tile
    int quad = lane >> 4;
    int e = e0 + col;
    int s = csr_src[e], d = csr_dst[e];
    int ch0 = cbase + quad * 4;

    short8v bh = *(const short8v*)(eah + (size_t)e * 32 + quad * 8);
    short8v bl = *(const short8v*)(eal + (size_t)e * 32 + quad * 8);

    const float* xls = xl + (size_t)s * stride + ch0;
    const float* xrd = xr + (size_t)d * stride + ch0;
    const float* atp = att + ch0;
    const short* wph = weTh + (size_t)(cbase + col) * 32 + quad * 8;
    const short* wpl = weTl + (size_t)(cbase + col) * 32 + quad * 8;

    int ntile = co >> 4;
    float p = 0.f;

    short8v ahA = *(const short8v*)wph;
    short8v alA = *(const short8v*)wpl;
    float4 lvA = *(const float4*)xls;
    float4 rvA = *(const float4*)xrd;
    float4 avA = *(const float4*)atp;

    for (int tt = 0; tt < ntile - 1; tt++) {
        short8v ahB = *(const short8v*)(wph + (size_t)(tt + 1) * 512);
        short8v alB = *(const short8v*)(wpl + (size_t)(tt + 1) * 512);
        float4 lvB = *(const float4*)(xls + (tt + 1) * 16);
        float4 rvB = *(const float4*)(xrd + (tt + 1) * 16);
        float4 avB = *(const float4*)(atp + (tt + 1) * 16);

        f32x4 ee = (f32x4)(0.f);
        ee = __builtin_amdgcn_mfma_f32_16x16x32_bf16(ahA, bl, ee, 0, 0, 0);
        ee = __builtin_amdgcn_mfma_f32_16x16x32_bf16(alA, bh, ee, 0, 0, 0);
        ee = __builtin_amdgcn_mfma_f32_16x16x32_bf16(ahA, bh, ee, 0, 0, 0);
        float m0 = lvA.x + rvA.x + ee[0];
        float m1 = lvA.y + rvA.y + ee[1];
        float m2 = lvA.z + rvA.z + ee[2];
        float m3 = lvA.w + rvA.w + ee[3];
        m0 = (m0 > 0.f) ? m0 : 0.2f * m0;
        m1 = (m1 > 0.f) ? m1 : 0.2f * m1;
        m2 = (m2 > 0.f) ? m2 : 0.2f * m2;
        m3 = (m3 > 0.f) ? m3 : 0.2f * m3;
        p += m0 * avA.x + m1 * avA.y + m2 * avA.z + m3 * avA.w;

        ahA = ahB; alA = alB; lvA = lvB; rvA = rvB; avA = avB;
    }
    {
        f32x4 ee = (f32x4)(0.f);
        ee = __builtin_amdgcn_mfma_f32_16x16x32_bf16(ahA, bl, ee, 0, 0, 0);
        ee = __builtin_amdgcn_mfma_f32_16x16x32_bf16(alA, bh, ee, 0, 0, 0);
        ee = __builtin_amdgcn_mfma_f32_16x16x32_bf16(ahA, bh, ee, 0, 0, 0);
        float m0 = lvA.x + rvA.x + ee[0];
        float m1 = lvA.y + rvA.y + ee[1];
        float m2 = lvA.z + rvA.z + ee[2];
        float m3 = lvA.w + rvA.w + ee[3];
        m0 = (m0 > 0.f) ? m0 : 0.2f * m0;
        m1 = (m1 > 0.f) ? m1 : 0.2f * m1;
        m2 = (m2 > 0.f) ? m2 : 0.2f * m2;
        m3 = (m3 > 0.f) ? m3 : 0.2f * m3;
        p += m0 * avA.x + m1 * avA.y + m2 * avA.z + m3 * avA.w;
    }

    p += __shfl_down(p, 32, 64);
    p += __shfl_down(p, 16, 64);
    if (lane < 16)
        logits[(size_t)(e0 + lane) * H + head] = p;
}

// ---------------- fused softmax + aggregation v5: bf16 hi/lo epilogue ----------------

__global__ __launch_bounds__(256) void aggregate5(
        const int* __restrict__ rowptr, const int* __restrict__ csr_src,
        const float* __restrict__ logits, const float* __restrict__ xl,
        const float* __restrict__ bias,
        short* __restrict__ outh, short* __restrict__ outl,
        float* __restrict__ outf, int last,
        int H, int co_shift, int hc, int stride) {
    __shared__ int ssrc[64];
    __shared__ float salp[64][4];
    __shared__ float sm[4], sinv[4];
    int n = blockIdx.x;
    int b = rowptr[n], t = rowptr[n + 1];
    int tid = threadIdx.x;
    int nthr = blockDim.x;

    if (tid < H) {
        float m = -1e30f;
        for (int i = b; i < t; i++)
            m = fmaxf(m, logits[(size_t)i * H + tid]);
        float s = 0.f;
        for (int i = b; i < t; i++)
            s += expf(logits[(size_t)i * H + tid] - m);
        sm[tid] = m;
        sinv[tid] = 1.f / s;    // self-loop guarantees s > 0
    }
    __syncthreads();

    int j0 = tid * 4;
    int j1 = j0 + nthr * 4;
    int h0 = j0 >> co_shift;
    int h1 = j1 >> co_shift;
    bool act1 = j1 < hc;

    float4 acc0 = make_float4(0.f, 0.f, 0.f, 0.f);
    float4 acc1 = make_float4(0.f, 0.f, 0.f, 0.f);

    for (int cb = b; cb < t; cb += 64) {
        int m = min(64, t - cb);
        __syncthreads();
        for (int i = tid; i < m; i += nthr) {
            ssrc[i] = csr_src[cb + i];
            for (int h = 0; h < H; h++)
                salp[i][h] = expf(logits[(size_t)(cb + i) * H + h] - sm[h]) * sinv[h];
        }
        __syncthreads();
        for (int i = 0; i < m; i++) {
            int s = ssrc[i];
            const float* base = xl + (size_t)s * stride;
            {
                float a = salp[i][h0];
                float4 v = *(const float4*)(base + j0);
                acc0.x += a * v.x; acc0.y += a * v.y;
                acc0.z += a * v.z; acc0.w += a * v.w;
            }
            if (act1) {
                float a = salp[i][h1];
                float4 v = *(const float4*)(base + j1);
                acc1.x += a * v.x; acc1.y += a * v.y;
                acc1.z += a * v.z; acc1.w += a * v.w;
            }
        }
    }

    float4 bz0 = *(const float4*)(bias + j0);
    float4 o0;
    o0.x = fmaxf(acc0.x + bz0.x, 0.f); o0.y = fmaxf(acc0.y + bz0.y, 0.f);
    o0.z = fmaxf(acc0.z + bz0.z, 0.f); o0.w = fmaxf(acc0.w + bz0.w, 0.f);
    if (last) {
        *(float4*)(outf + (size_t)n * hc + j0) = o0;
    } else {
        unsigned short hx = f2bf(o0.x), hy = f2bf(o0.y), hz = f2bf(o0.z), hw = f2bf(o0.w);
        short4v hv = { (short)hx, (short)hy, (short)hz, (short)hw };
        short4v lv = { (short)f2bf(o0.x - bf2f(hx)), (short)f2bf(o0.y - bf2f(hy)),
                       (short)f2bf(o0.z - bf2f(hz)), (short)f2bf(o0.w - bf2f(hw)) };
        *(short4v*)(outh + (size_t)n * hc + j0) = hv;
        *(short4v*)(outl + (size_t)n * hc + j0) = lv;
    }
    if (act1) {
        float4 bz1 = *(const float4*)(bias + j1);
        float4 o1;
        o1.x = fmaxf(acc1.x + bz1.x, 0.f); o1.y = fmaxf(acc1.y + bz1.y, 0.f);
        o1.z = fmaxf(acc1.z + bz1.z, 0.f); o1.w = fmaxf(acc1.w + bz1.w, 0.f);
        if (last) {
            *(float4*)(outf + (size_t)n * hc + j1) = o1;
        } else {
            unsigned short hx = f2bf(o1.x), hy = f2bf(o1.y), hz = f2bf(o1.z), hw = f2bf(o1.w);
            short4v hv = { (short)hx, (short)hy, (short)hz, (short)hw };
            short4v lv = { (short)f2bf(o1.x - bf2f(hx)), (short)f2bf(o1.y - bf2f(hy)),
                           (short)f2bf(o1.z - bf2f(hz)), (short)f2bf(o1.w - bf2f(hw)) };
            *(short4v*)(outh + (size_t)n * hc + j1) = hv;
            *(short4v*)(outl + (size_t)n * hc + j1) = lv;
        }
    }
}

// ---------------- pooling + MLP head ----------------

__global__ void pool_cnt(const int* __restrict__ batch, int* __restrict__ gcnt) {
    int n = blockIdx.x * 256 + threadIdx.x;
    if (n < N_NODES) atomicAdd(&gcnt[batch[n]], 1);
}

__global__ void pool_sum(const int* __restrict__ batch, const float* __restrict__ h,
                         float* __restrict__ pooled) {
    int tid = blockIdx.x * 256 + threadIdx.x;
    if (tid >= N_NODES * 256) return;
    int n = tid >> 8, c = tid & 255;
    atomicAdd(&pooled[batch[n] * 256 + c], h[tid]);
}

__global__ void mlp_head(const float* __restrict__ pooled, const int* __restrict__ gcnt,
                         const float* __restrict__ fc1w, const float* __restrict__ fc1b,
                         const float* __restrict__ fc2w, const float* __restrict__ fc2b,
                         float* __restrict__ out) {
    int g = threadIdx.x;
    if (g >= NGRAPHS) return;
    float inv = 1.f / (float)(gcnt[g] > 0 ? gcnt[g] : 1);
    float s[64];
#pragma unroll
    for (int j = 0; j < 64; j++) s[j] = fc1b[j];
    for (int c = 0; c < 256; c++) {
        float mv = pooled[g * 256 + c] * inv;
#pragma unroll
        for (int j = 0; j < 64; j++) s[j] += mv * fc1w[c * 64 + j];
    }
    float o = 0.f;
#pragma unroll
    for (int j = 0; j < 64; j++) o += fmaxf(s[j], 0.f) * fc2w[j];
    out[g] = o + fc2b[0];
}

// ---------------- launch ----------------

extern "C" void kernel_launch(void* const* d_in, const int* in_sizes, int n_in,
                              void* d_out, int out_size, void* d_ws, size_t ws_size,
                              hipStream_t stream) {
    const float* x         = (const float*)d_in[0];
    const int*   edge_index= (const int*)d_in[1];
    const float* edge_attr = (const float*)d_in[2];
    const int*   batch     = (const int*)d_in[3];
    const int* src0 = edge_index;
    const int* dst0 = edge_index + N_EDGES;

    const float *Wl[4], *bl[4], *Wr[4], *br[4], *We[4], *att[4], *bias[4];
    for (int i = 0; i < 4; i++) {
        int base = 4 + 7 * i;
        Wl[i]   = (const float*)d_in[base + 0];
        bl[i]   = (const float*)d_in[base + 1];
        Wr[i]   = (const float*)d_in[base + 2];
        br[i]   = (const float*)d_in[base + 3];
        We[i]   = (const float*)d_in[base + 4];
        att[i]  = (const float*)d_in[base + 5];
        bias[i] = (const float*)d_in[base + 6];
    }
    const float* fc1w = (const float*)d_in[32];
    const float* fc1b = (const float*)d_in[33];
    const float* fc2w = (const float*)d_in[34];
    const float* fc2b = (const float*)d_in[35];
    float* out = (float*)d_out;

    // workspace layout (float offsets); end unchanged at 56493824 floats (~226 MB, verified)
    float* ws = (float*)d_ws;
    int*   rowptr  = (int*)(ws + 0);            // 8001
    int*   woff    = (int*)(ws + 8064);         // 8000
    int*   eid     = (int*)(ws + 16128);        // 72000
    int*   csr_src = (int*)(ws + 88128);        // 72000
    int*   csr_dst = (int*)(ws + 160128);       // 72000
    float* ea_loop = ws + 232128;               // 8000*16 -> ends 360128
    short* weTh_a  = (short*)(ws + 360128);     // 3328*32 shorts = 53248 floats
    short* weTl_a  = (short*)(ws + 413376);     // -> ends 466624 (old ea_csr hole)
    float* logits  = ws + 1512128;              // 72000*3
    float* xlr     = ws + 1728128;              // 8000*3072 (xl | xr fused, stride 2hc)
    float* hbF     = xlr + 24576000;            // final-layer fp32 out (8000*256 used)
    float* pooled  = hbF + 12288000;            // 16384
    int*   gcnt    = (int*)(pooled + 16384);    // 64 -> pad to 38608640
    short* wth     = (short*)(ws + 38608640);   // max 2*1536*1024 shorts = 1572864 floats
    short* wtl     = (short*)(ws + 40181504);   // -> ends 41754368
    short* eah     = (short*)(ws + 41754368);   // 72000*32 shorts = 1152000 floats
    short* eal     = (short*)(ws + 42906368);   // -> ends 44058368
    short* acth    = (short*)(ws + 44107520);   // 8064*1536 shorts = 6193152 floats
    short* actl    = (short*)(ws + 50300672);   // -> ends 56493824

    hipMemsetAsync(woff, 0, N_NODES * sizeof(int), stream);
    count_deg<<<(N_EDGES + 255) / 256, 256, 0, stream>>>(dst0, woff);
    scan_deg2<<<1, 256, 0, stream>>>(woff, rowptr, woff);
    fill_eid<<<(ETOT + 255) / 256, 256, 0, stream>>>(dst0, woff, eid);
    csr_fill_dst<<<(N_NODES + 255) / 256, 256, 0, stream>>>(rowptr, csr_dst);
    ea_loop_kernel<<<(N_NODES + 255) / 256, 256, 0, stream>>>(rowptr, eid, edge_attr, ea_loop);
    csr_srcea_bf<<<(ETOT * 4 + 255) / 256, 256, 0, stream>>>(eid, src0, edge_attr, ea_loop,
                                                             csr_src, eah, eal);
    cvt_we_all<<<(3328 + 255) / 256, 256, 0, stream>>>(We[0], We[1], We[2], We[3],
                                                       weTh_a, weTl_a);
    // layer-1 input split (later layers' splits come from aggregate5 epilogue)
    cvt_act<<<(N_NODES * 256 / 4 + 255) / 256, 256, 0, stream>>>(x, acth, actl, N_NODES * 256);

    const int IN[4] = {256, 1536, 1024, 512};
    const int HH[4] = {3, 2, 2, 1};
    const int CO[4] = {512, 512, 256, 256};
    const int CS[4] = {9, 9, 8, 8};            // log2(co)
    const int CHOFF[4] = {0, 1536, 2560, 3072}; // weT channel offsets

    for (int L = 0; L < 4; L++) {
        int K = IN[L], H = HH[L], co = CO[L], hc = H * co, cs = CS[L];
        int hc2 = 2 * hc;
        dim3 gg(hc2 / 128, (N_NODES + 127) / 128);
        dim3 gw(hc / 32, K / 32, 2);
        cvt_wt_t2<<<gw, 256, 0, stream>>>(Wl[L], Wr[L], wth, wtl, K, hc);
        gemm_mfma2<<<gg, 256, 0, stream>>>(acth, actl, wth, wtl,
                                           bl[L], br[L], hc, xlr, N_NODES, K, hc2);
        dim3 gl(ETOT / 64, H);
        edge_logits7<<<gl, 256, 0, stream>>>(
            xlr, xlr + hc,
            weTh_a + (size_t)CHOFF[L] * 32, weTl_a + (size_t)CHOFF[L] * 32,
            att[L], eah, eal, csr_src, csr_dst, logits, H, co, hc2);
        int athr = hc / 4 > 256 ? 256 : hc / 4;
        aggregate5<<<N_NODES, athr, 0, stream>>>(
            rowptr, csr_src, logits, xlr, bias[L],
            acth, actl, hbF, (L == 3) ? 1 : 0, H, cs, hc, hc2);
    }

    hipMemsetAsync(pooled, 0, (16384 + 64) * sizeof(float), stream);
    pool_cnt<<<(N_NODES + 255) / 256, 256, 0, stream>>>(batch, gcnt);
    pool_sum<<<(N_NODES * 256 + 255) / 256, 256, 0, stream>>>(batch, hbF, pooled);
    mlp_head<<<1, 64, 0, stream>>>(pooled, gcnt, fc1w, fc1b, fc2w, fc2b, out);
}